// Round 9
// baseline (1031.987 us; speedup 1.0000x reference)
//
#include <hip/hip_runtime.h>
#include <stdint.h>

#define NB 8
#define NN 2048
#define NU 256
#define CAP 64
#define BNEPS 0.001f

typedef __attribute__((ext_vector_type(8))) short short8;
typedef __attribute__((ext_vector_type(4))) float floatx4;
typedef unsigned short u16;
typedef unsigned int u32;

__device__ __forceinline__ float bf2f(u16 u) {
  union { u32 i; float f; } c; c.i = ((u32)u) << 16; return c.f;
}
__device__ __forceinline__ float bflo(u32 p) {  // low packed bf16 -> f32
  union { u32 i; float f; } c; c.i = p << 16; return c.f;
}
__device__ __forceinline__ float bfhi(u32 p) {  // high packed bf16 -> f32
  union { u32 i; float f; } c; c.i = p & 0xffff0000u; return c.f;
}
__device__ __forceinline__ u16 f2bf(float f) {
  union { float f; u32 i; } c; c.f = f;
  return (u16)((c.i + 0x7fffu + ((c.i >> 16) & 1u)) >> 16);
}
// bf16 hi/lo split: a = bf2f(h) + bf2f(l) + O(2^-18 |a|)
__device__ __forceinline__ void splitbf(float a, u16& h, u16& l) {
  h = f2bf(a);
  l = f2bf(a - bf2f(h));
}

enum : unsigned {
  F_BIAS = 2u, F_SILU = 4u, F_MASKPRE = 8u, F_MASKPOST = 16u,
  F_ADDX = 32u, F_BN = 64u, F_ADDT = 128u, F_ASHARED = 256u, F_BPERMAT = 512u,
  F_TPLANES = 1024u, F_OUTHL = 2048u
};

#define TP_MAT 524288   // per-batch transposed plane: 256 cols x 2048 rows (u16)
#define TP_LO  4194304  // transposed lo plane offset (u16 elems)
#define MSZ ((size_t)NN * NU)

// ---------------------------------------------------------------------------
// Neighbor-list build: one block per (b, m) row of adj; values are exactly 0/1.
// ---------------------------------------------------------------------------
__global__ __launch_bounds__(256) void build_nbr_k(
    const float* __restrict__ adj, int* __restrict__ cnt, int* __restrict__ idx)
{
  int row = blockIdx.x;  // b*NN + m
  const float* base = adj + (size_t)row * NN;
  __shared__ int c;
  if (threadIdx.x == 0) c = 0;
  __syncthreads();
#pragma unroll
  for (int j = 0; j < 8; j++) {
    int n = j * 256 + threadIdx.x;  // coalesced
    if (base[n] != 0.f) {
      int p = atomicAdd(&c, 1);
      if (p < CAP) idx[(size_t)row * CAP + p] = n;
    }
  }
  __syncthreads();
  if (threadIdx.x == 0) cnt[row] = (c < CAP ? c : CAP);
}

// ---------------------------------------------------------------------------
// Weight conversion: f32 [K=256][N=256] -> TWO bf16 swizzled-B^T planes
// dst[kb][n][slot][j] = part(W[kb*32 + qv*8 + j][n]), qv = (slot - (n>>1)) & 3
// ---------------------------------------------------------------------------
struct WPtrs { const float* p[16]; };

__global__ __launch_bounds__(256) void conv_w_k(WPtrs wp, u16* __restrict__ dst)
{
  int gid = blockIdx.x * 256 + threadIdx.x;  // 16 mats * 8192 chunks
  int mat = gid >> 13;
  int rem = gid & 8191;
  int kb = rem >> 10;
  int n = (rem >> 2) & 255;
  int slot = rem & 3;
  int qv = (slot - (n >> 1)) & 3;
  int k0 = kb * 32 + qv * 8;
  const float* W = wp.p[mat];
  u32 oh[4], ol[4];
#pragma unroll
  for (int t2 = 0; t2 < 4; t2++) {
    float f0 = W[(size_t)(k0 + 2 * t2) * 256 + n];
    float f1 = W[(size_t)(k0 + 2 * t2 + 1) * 256 + n];
    u16 h0, l0, h1, l1;
    splitbf(f0, h0, l0);
    splitbf(f1, h1, l1);
    oh[t2] = (u32)h0 | ((u32)h1 << 16);
    ol[t2] = (u32)l0 | ((u32)l1 << 16);
  }
  uint4 qh; qh.x = oh[0]; qh.y = oh[1]; qh.z = oh[2]; qh.w = oh[3];
  uint4 ql; ql.x = ol[0]; ql.y = ol[1]; ql.z = ol[2]; ql.w = ol[3];
  *(uint4*)(dst + (size_t)gid * 8) = qh;
  *(uint4*)(dst + 1048576 + (size_t)gid * 8) = ql;  // lo plane at +16*65536
}

// Convert fp32 x (8 mats) -> row-major hi/lo bf16 planes (lo at +oLo elems).
__global__ __launch_bounds__(256) void conv_x_k(
    const float* __restrict__ x, u16* __restrict__ dst, size_t oLo)
{
  size_t i = ((size_t)blockIdx.x * 256 + threadIdx.x) * 4;
  float4 v = *(const float4*)(x + i);
  u16 h0, l0, h1, l1, h2, l2, h3, l3;
  splitbf(v.x, h0, l0); splitbf(v.y, h1, l1);
  splitbf(v.z, h2, l2); splitbf(v.w, h3, l3);
  uint2 H; H.x = (u32)h0 | ((u32)h1 << 16); H.y = (u32)h2 | ((u32)h3 << 16);
  uint2 L; L.x = (u32)l0 | ((u32)l1 << 16); L.y = (u32)l2 | ((u32)l3 << 16);
  *(uint2*)(dst + i) = H;
  *(uint2*)(dst + oLo + i) = L;
}

// ---------------------------------------------------------------------------
// Dense GEMM, fp32-emulated via bf16 hi/lo 3-term MFMA.
// Tile: 64 rows x 256 cols, 512 thr (8 waves: 2 row-groups x 4 col-groups).
// A: pre-split hi/lo planes, pure-copy staged to LDS (67.6 KB -> 2 blocks/CU).
// B: per-lane fragments straight from swizzled global planes (L2-hot).
// Barrier-free K-loop after one staging barrier. Grid 1-D, xcd = id&7.
// ---------------------------------------------------------------------------
template <unsigned F, int NG>
__global__ __launch_bounds__(512, 4) void gemm_k(
    const u16* __restrict__ Abase, size_t aLo,
    const u16* __restrict__ W0, const u16* __restrict__ W1, const u16* __restrict__ W2,
    size_t wLo,
    const float* __restrict__ b0, const float* __restrict__ b1, const float* __restrict__ b2,
    const float* __restrict__ mask,
    const float* __restrict__ xf32,
    const float* __restrict__ gma, const float* __restrict__ bta,
    const float* __restrict__ bmu, const float* __restrict__ bvr,
    const float* __restrict__ addt,
    void* __restrict__ outp, size_t oLo)
{
  const int tid = threadIdx.x;
  const int id = blockIdx.x;
  const int xcd = id & 7;
  const int t = id >> 3;
  const int chain = (NG == 1) ? 0 : (t % NG);
  const int xt = (NG == 1) ? t : (t / NG);
  const int mat = chain * 8 + xcd;
  const int b = xcd;
  const int bm = xt * 64;

  __shared__ alignas(16) u16 Ah[64 * 264];  // 33792 B
  __shared__ alignas(16) u16 Al[64 * 264];  // 33792 B -> 67584 B total

  const u16* Whi = (F & F_BPERMAT) ? (W0 + (size_t)mat * 65536)
                                   : (chain == 0 ? W0 : (chain == 1 ? W1 : W2));
  const u16* Wlo = Whi + wLo;
  const float* bsel = (chain == 0 ? b0 : (chain == 1 ? b1 : b2));
  const u16* Ahp = Abase + ((F & F_ASHARED) ? (size_t)b : (size_t)mat) * MSZ;
  const u16* Alp = Ahp + aLo;

  // ---- stage A tile (64 x 256) hi/lo: pure copies ----
#pragma unroll
  for (int s = tid; s < 1024; s += 512) {
    int r = s >> 4;
    int c = (s & 15) << 4;
    size_t ao = (size_t)(bm + r) * 256 + c;
    *(uint4*)&Ah[r * 264 + c] = *(const uint4*)(Ahp + ao);
    *(uint4*)&Ah[r * 264 + c + 8] = *(const uint4*)(Ahp + ao + 8);
    *(uint4*)&Al[r * 264 + c] = *(const uint4*)(Alp + ao);
    *(uint4*)&Al[r * 264 + c + 8] = *(const uint4*)(Alp + ao + 8);
  }
  __syncthreads();

  const int lane = tid & 63;
  const int w = tid >> 6;      // 8 waves
  const int wr = w >> 2;       // row group 0..1 (32 rows each)
  const int wc = w & 3;        // col group 0..3 (64 cols each)
  const int m16 = lane & 15;
  const int q = lane >> 4;

  floatx4 acc[2][4];
#pragma unroll
  for (int i = 0; i < 2; i++)
#pragma unroll
    for (int j = 0; j < 4; j++) acc[i][j] = (floatx4){0.f, 0.f, 0.f, 0.f};

#pragma unroll
  for (int kk = 0; kk < 8; kk++) {
    short8 bh[4], bl2[4];
#pragma unroll
    for (int nt = 0; nt < 4; nt++) {
      int n = wc * 64 + nt * 16 + m16;
      size_t off = (size_t)kk * 8192 + (size_t)n * 32 + (size_t)(((q + (n >> 1)) & 3) * 8);
      bh[nt] = *(const short8*)(Whi + off);
      bl2[nt] = *(const short8*)(Wlo + off);
    }
#pragma unroll
    for (int mt = 0; mt < 2; mt++) {
      int row = wr * 32 + mt * 16 + m16;
      short8 ah = *(const short8*)&Ah[row * 264 + kk * 32 + q * 8];
      short8 al2 = *(const short8*)&Al[row * 264 + kk * 32 + q * 8];
#pragma unroll
      for (int nt = 0; nt < 4; nt++) {
        acc[mt][nt] = __builtin_amdgcn_mfma_f32_16x16x32_bf16(ah, bh[nt], acc[mt][nt], 0, 0, 0);
        acc[mt][nt] = __builtin_amdgcn_mfma_f32_16x16x32_bf16(al2, bh[nt], acc[mt][nt], 0, 0, 0);
        acc[mt][nt] = __builtin_amdgcn_mfma_f32_16x16x32_bf16(ah, bl2[nt], acc[mt][nt], 0, 0, 0);
      }
    }
  }

  // ---- epilogue ----
#pragma unroll
  for (int mt = 0; mt < 2; mt++) {
    if (F & F_TPLANES) {
      // transposed bf16 hi/lo planes: oT[col][row], per batch b
      u16* oh = (u16*)outp + (size_t)b * TP_MAT;
      u16* ol = oh + TP_LO;
      int gr0 = bm + wr * 32 + mt * 16 + q * 4;
#pragma unroll
      for (int nt = 0; nt < 4; nt++) {
        int col = wc * 64 + nt * 16 + m16;
        u16 hh[4], ll[4];
#pragma unroll
        for (int r = 0; r < 4; r++) {
          float t2 = acc[mt][nt][r];
          float mv = mask[b * NN + gr0 + r];
          if (F & F_MASKPRE) t2 *= mv;
          if (F & F_SILU) t2 = t2 / (1.f + __expf(-t2));
          if (F & F_MASKPOST) t2 *= mv;
          splitbf(t2, hh[r], ll[r]);
        }
        uint2 H2, L2v;
        H2.x = (u32)hh[0] | ((u32)hh[1] << 16);
        H2.y = (u32)hh[2] | ((u32)hh[3] << 16);
        L2v.x = (u32)ll[0] | ((u32)ll[1] << 16);
        L2v.y = (u32)ll[2] | ((u32)ll[3] << 16);
        *(uint2*)(oh + (size_t)col * 2048 + gr0) = H2;
        *(uint2*)(ol + (size_t)col * 2048 + gr0) = L2v;
      }
    } else {
#pragma unroll
      for (int r = 0; r < 4; r++) {
        int gr = bm + wr * 32 + mt * 16 + q * 4 + r;
        float mval = 1.f;
        if (F & (F_MASKPRE | F_MASKPOST)) mval = mask[b * NN + gr];
#pragma unroll
        for (int nt = 0; nt < 4; nt++) {
          int col = wc * 64 + nt * 16 + m16;
          float t2 = acc[mt][nt][r];
          if (F & F_BIAS) t2 += bsel[col];
          if (F & F_MASKPRE) t2 *= mval;
          if (F & F_SILU) t2 = t2 / (1.f + __expf(-t2));
          if (F & F_ADDX) t2 += xf32[((size_t)b * NN + gr) * NU + col];
          if (F & F_BN) t2 = gma[col] * (t2 - bmu[col]) * rsqrtf(bvr[col] + BNEPS) + bta[col];
          if (F & F_ADDT) t2 += addt[((size_t)mat * NN + gr) * NU + col];
          if (F & F_MASKPOST) t2 *= mval;
          size_t o = ((size_t)mat * NN + gr) * NU + col;
          if (F & F_OUTHL) {
            u16 h0, l0;
            splitbf(t2, h0, l0);
            ((u16*)outp)[o] = h0;
            ((u16*)outp)[o + oLo] = l0;
          } else {
            ((float*)outp)[o] = t2;
          }
        }
      }
    }
  }
}

// ---------------------------------------------------------------------------
// Fused 3-chain gather: x'[c][m] = epi( sum_{n in nbr(m)} g[c][n] + bias[c] ).
// g is bf16 hi/lo planes (lo at +gLo): per-(chain,b) footprint 2 MB -> fits
// per-XCD L2 with room to spare. Out: hi/lo bf16 planes (lo at +oLo).
// One wave per row. Grid 12288, chain-major (c = id>>12).
// ---------------------------------------------------------------------------
template <unsigned F>
__global__ __launch_bounds__(256, 8) void agg_k(
    const u16* __restrict__ g, size_t gLo, u16* __restrict__ xo, size_t oLo,
    const float* __restrict__ bq, const float* __restrict__ bk, const float* __restrict__ bv,
    const float* __restrict__ mask,
    const int* __restrict__ ncnt, const int* __restrict__ nidx)
{
  int id = blockIdx.x;
  int c3 = id >> 12;       // chain 0..2
  int sub = id & 4095;
  int b = sub & 7;
  int rg = sub >> 3;
  int tid = threadIdx.x;
  int w = tid >> 6;
  int l = tid & 63;
  int row = rg * 4 + w;
  int rowid = b * NN + row;
  const u16* __restrict__ gh = g + ((size_t)c3 * 8 + b) * MSZ;
  const u16* __restrict__ gl = gh + gLo;
  const float* bias = (c3 == 0) ? bq : (c3 == 1 ? bk : bv);
  int cnt = ncnt[rowid];
  const int* __restrict__ ip = nidx + (size_t)rowid * CAP;
  int c = l * 4;
  float a0 = 0.f, a1 = 0.f, a2 = 0.f, a3 = 0.f;
  int e = 0;
  for (; e + 4 <= cnt; e += 4) {
    int4 i4 = *(const int4*)(ip + e);
    size_t r0 = ((size_t)i4.x << 8) + c;
    size_t r1 = ((size_t)i4.y << 8) + c;
    size_t r2 = ((size_t)i4.z << 8) + c;
    size_t r3 = ((size_t)i4.w << 8) + c;
    uint2 h0 = *(const uint2*)(gh + r0), l0v = *(const uint2*)(gl + r0);
    uint2 h1 = *(const uint2*)(gh + r1), l1v = *(const uint2*)(gl + r1);
    uint2 h2 = *(const uint2*)(gh + r2), l2v = *(const uint2*)(gl + r2);
    uint2 h3 = *(const uint2*)(gh + r3), l3v = *(const uint2*)(gl + r3);
    a0 += bflo(h0.x) + bflo(l0v.x) + bflo(h1.x) + bflo(l1v.x)
        + bflo(h2.x) + bflo(l2v.x) + bflo(h3.x) + bflo(l3v.x);
    a1 += bfhi(h0.x) + bfhi(l0v.x) + bfhi(h1.x) + bfhi(l1v.x)
        + bfhi(h2.x) + bfhi(l2v.x) + bfhi(h3.x) + bfhi(l3v.x);
    a2 += bflo(h0.y) + bflo(l0v.y) + bflo(h1.y) + bflo(l1v.y)
        + bflo(h2.y) + bflo(l2v.y) + bflo(h3.y) + bflo(l3v.y);
    a3 += bfhi(h0.y) + bfhi(l0v.y) + bfhi(h1.y) + bfhi(l1v.y)
        + bfhi(h2.y) + bfhi(l2v.y) + bfhi(h3.y) + bfhi(l3v.y);
  }
  for (; e < cnt; e++) {
    size_t r0 = ((size_t)ip[e] << 8) + c;
    uint2 h0 = *(const uint2*)(gh + r0), l0v = *(const uint2*)(gl + r0);
    a0 += bflo(h0.x) + bflo(l0v.x);
    a1 += bfhi(h0.x) + bfhi(l0v.x);
    a2 += bflo(h0.y) + bflo(l0v.y);
    a3 += bfhi(h0.y) + bfhi(l0v.y);
  }
  float4 bb = *(const float4*)(bias + c);
  float o[4] = {a0 + bb.x, a1 + bb.y, a2 + bb.z, a3 + bb.w};
  float mv = (F & F_MASKPOST) ? mask[rowid] : 1.f;
  u16 hh[4], ll[4];
#pragma unroll
  for (int j = 0; j < 4; j++) {
    float t = o[j];
    if (F & F_SILU) t = t / (1.f + __expf(-t));
    if (F & F_MASKPOST) t *= mv;
    splitbf(t, hh[j], ll[j]);
  }
  uint2 H; H.x = (u32)hh[0] | ((u32)hh[1] << 16); H.y = (u32)hh[2] | ((u32)hh[3] << 16);
  uint2 L; L.x = (u32)ll[0] | ((u32)ll[1] << 16); L.y = (u32)ll[2] | ((u32)ll[3] << 16);
  size_t o0 = ((size_t)c3 * 8 + b) * MSZ + ((size_t)row << 8) + c;
  *(uint2*)(xo + o0) = H;
  *(uint2*)(xo + oLo + o0) = L;
}

// ---------------------------------------------------------------------------
// kv[d][e] = sum_n pk[n][d] * pv[n][e], from transposed bf16 hi/lo planes.
// LDS-free, 3-term. Split-K=8: part[z = p*8+b][d][e], grid (2,2,64).
// ---------------------------------------------------------------------------
__global__ __launch_bounds__(256, 2) void kv_k(
    const u16* __restrict__ pkT, const u16* __restrict__ pvT, float* __restrict__ part)
{
  int et = blockIdx.x * 128;
  int dt = blockIdx.y * 128;
  int z = blockIdx.z;
  int b = z & 7;
  int p = z >> 3;
  int tid = threadIdx.x;
  int lane = tid & 63, w = tid >> 6;
  int m16 = lane & 15, q = lane >> 4;

  const u16* pkh = pkT + (size_t)b * TP_MAT;
  const u16* pkl = pkh + TP_LO;
  const u16* pvh = pvT + (size_t)b * TP_MAT;
  const u16* pvl = pvh + TP_LO;

  int d_base = dt + (w >> 1) * 64 + m16;
  int e_base = et + (w & 1) * 64 + m16;

  floatx4 acc[4][4];
#pragma unroll
  for (int i = 0; i < 4; i++)
#pragma unroll
    for (int j = 0; j < 4; j++) acc[i][j] = (floatx4){0.f, 0.f, 0.f, 0.f};

#pragma unroll
  for (int kt = 0; kt < 8; kt++) {
    int kc = p * 256 + kt * 32 + q * 8;
    short8 ah[4], al[4], bh[4], bl[4];
#pragma unroll
    for (int mt = 0; mt < 4; mt++) {
      size_t o = (size_t)(d_base + mt * 16) * 2048 + kc;
      ah[mt] = *(const short8*)(pkh + o);
      al[mt] = *(const short8*)(pkl + o);
    }
#pragma unroll
    for (int nt = 0; nt < 4; nt++) {
      size_t o = (size_t)(e_base + nt * 16) * 2048 + kc;
      bh[nt] = *(const short8*)(pvh + o);
      bl[nt] = *(const short8*)(pvl + o);
    }
#pragma unroll
    for (int mt = 0; mt < 4; mt++)
#pragma unroll
      for (int nt = 0; nt < 4; nt++) {
        acc[mt][nt] = __builtin_amdgcn_mfma_f32_16x16x32_bf16(ah[mt], bh[nt], acc[mt][nt], 0, 0, 0);
        acc[mt][nt] = __builtin_amdgcn_mfma_f32_16x16x32_bf16(al[mt], bh[nt], acc[mt][nt], 0, 0, 0);
        acc[mt][nt] = __builtin_amdgcn_mfma_f32_16x16x32_bf16(ah[mt], bl[nt], acc[mt][nt], 0, 0, 0);
      }
  }

#pragma unroll
  for (int mt = 0; mt < 4; mt++)
#pragma unroll
    for (int r = 0; r < 4; r++) {
      int d = dt + (w >> 1) * 64 + mt * 16 + q * 4 + r;
#pragma unroll
      for (int nt = 0; nt < 4; nt++) {
        int e = et + (w & 1) * 64 + nt * 16 + m16;
        part[(size_t)z * 65536 + (size_t)d * 256 + e] = acc[mt][nt][r];
      }
    }
}

// Reduce split-K partials (8 p-planes) and emit kv bf16 hi/lo swizzled planes.
__global__ __launch_bounds__(256) void kv_conv_k(const float* __restrict__ part, u16* __restrict__ dst)
{
  int gid = blockIdx.x * 256 + threadIdx.x;  // 8 * 8192 = 65536
  int b = gid >> 13;
  int rem = gid & 8191;
  int kb = rem >> 10;
  int e = (rem >> 2) & 255;
  int slot = rem & 3;
  int qv = (slot - (e >> 1)) & 3;
  int d0 = kb * 32 + qv * 8;
  const float* src = part + (size_t)b * 65536 + (size_t)d0 * 256 + e;
  u32 oh[4], ol[4];
#pragma unroll
  for (int t2 = 0; t2 < 4; t2++) {
    float s0 = 0.f, s1 = 0.f;
#pragma unroll
    for (int pp = 0; pp < 8; pp++) {
      const float* sp = src + (size_t)pp * 524288 + t2 * 512;
      s0 += sp[0];
      s1 += sp[256];
    }
    u16 h0, l0, h1, l1;
    splitbf(s0, h0, l0);
    splitbf(s1, h1, l1);
    oh[t2] = (u32)h0 | ((u32)h1 << 16);
    ol[t2] = (u32)l0 | ((u32)l1 << 16);
  }
  uint4 qh; qh.x = oh[0]; qh.y = oh[1]; qh.z = oh[2]; qh.w = oh[3];
  uint4 ql; ql.x = ol[0]; ql.y = ol[1]; ql.z = ol[2]; ql.w = ol[3];
  *(uint4*)(dst + (size_t)gid * 8) = qh;
  *(uint4*)(dst + 524288 + (size_t)gid * 8) = ql;  // lo plane at +8*65536
}

// ---------------------------------------------------------------------------
extern "C" void kernel_launch(void* const* d_in, const int* in_sizes, int n_in,
                              void* d_out, int out_size, void* d_ws, size_t ws_size,
                              hipStream_t stream)
{
  const float* x = (const float*)d_in[0];
  const float* adj = (const float*)d_in[1];
  const float* mask = (const float*)d_in[2];
  const float* W_lin = (const float*)d_in[3];
  const float* b_lin = (const float*)d_in[4];
  const float* Wq_mp = (const float*)d_in[5];
  const float* bq_mp = (const float*)d_in[6];
  const float* Wk_mp = (const float*)d_in[7];
  const float* bk_mp = (const float*)d_in[8];
  const float* Wv_mp = (const float*)d_in[9];
  const float* bv_mp = (const float*)d_in[10];
  const float* Wk_att = (const float*)d_in[11];
  const float* Wv_att = (const float*)d_in[12];
  const float* Wq_att = (const float*)d_in[13];
  const float* Wo_att = (const float*)d_in[14];
  const float* bn_gamma = (const float*)d_in[15];
  const float* bn_beta = (const float*)d_in[16];
  const float* bn_mean = (const float*)d_in[17];
  const float* bn_var = (const float*)d_in[18];
  const float* W_proj = (const float*)d_in[19];
  const float* b_proj = (const float*)d_in[20];
  const float* W_res = (const float*)d_in[21];
  const float* b_res = (const float*)d_in[22];

  char* ws = (char*)d_ws;
  int* CNT    = (int*)(ws + 0);                 // 64 KB
  int* IDX    = (int*)(ws + (1ull << 20));      // 4 MB
  u16* WSZ    = (u16*)(ws + (5ull << 20));      // 4 MB (bf16 hi 2MB + lo 2MB)
  u16* KVS    = (u16*)(ws + (9ull << 20));      // 2 MB
  float* KVP  = (float*)(ws + (11ull << 20));   // 16 MB
  u16* XHL    = (u16*)(ws + (27ull << 20));     // 16 MB (8 hi + 8 lo)
  u16* HHL    = (u16*)(ws + (43ull << 20));     // 16 MB (8 hi + 8 lo)
  u16* G      = (u16*)(ws + (59ull << 20));     // 48 MB bf16 hi/lo (24 mats)
  u16* XA     = (u16*)(ws + (107ull << 20));    // 48 MB (24 hi + 24 lo)
  u16* XB     = (u16*)(ws + (155ull << 20));    // 48 MB -> total 203 MB

  const size_t WLO = 1048576;   // weight lo-plane offset (u16 elems)
  const size_t KLO = 524288;    // kv lo-plane offset
  const size_t A8  = 8 * MSZ;   // lo offset for 8-mat hi/lo buffers
  const size_t A24 = 24 * MSZ;  // lo offset for 24-mat hi/lo buffers

  u16* PQHL = HHL;                         // h dead after s0 GEMM
  u16* PKT = G;                            // G dead after s5 agg
  u16* PVT = (u16*)((char*)G + (16ull << 20));
  u16* ATT = (u16*)((char*)G + (32ull << 20));
  u16* YHL = XA;                           // XA dead after s5 GEMM
  float* TMP = (float*)((char*)XA + (16ull << 20));

  // --- conversions + neighbor lists ---
  WPtrs wp;
  wp.p[0] = W_lin;
  wp.p[1] = Wq_mp; wp.p[2] = Wq_mp + 65536; wp.p[3] = Wq_mp + 131072;
  wp.p[4] = Wk_mp; wp.p[5] = Wk_mp + 65536; wp.p[6] = Wk_mp + 131072;
  wp.p[7] = Wv_mp; wp.p[8] = Wv_mp + 65536; wp.p[9] = Wv_mp + 131072;
  wp.p[10] = Wk_att; wp.p[11] = Wv_att; wp.p[12] = Wq_att; wp.p[13] = Wo_att;
  wp.p[14] = W_proj; wp.p[15] = W_res;
  conv_w_k<<<512, 256, 0, stream>>>(wp, WSZ);
  conv_x_k<<<4096, 256, 0, stream>>>(x, XHL, A8);
  build_nbr_k<<<NB * NN, 256, 0, stream>>>(adj, CNT, IDX);

  // --- h = x @ W_lin + b_lin -> hi/lo planes ---
  gemm_k<F_BIAS | F_OUTHL, 1><<<256, 512, 0, stream>>>(XHL, A8,
      WSZ, nullptr, nullptr, WLO, b_lin, nullptr, nullptr, nullptr, nullptr,
      bn_gamma, bn_beta, bn_mean, bn_var, nullptr, HHL, A8);

  // --- 6 mp steps: g = x@W (dense, hi/lo out), x' = silu(adj@g + b) (gather) ---
  u16* xbufs[2] = {XA, XB};
  for (int s = 0; s < 6; s++) {
    int i = s >> 1;
    const u16* Wq_s = WSZ + (size_t)(1 + i) * 65536;
    const u16* Wk_s = WSZ + (size_t)(4 + i) * 65536;
    const u16* Wv_s = WSZ + (size_t)(7 + i) * 65536;
    u16* inb = (s == 0) ? HHL : xbufs[(s + 1) & 1];
    u16* ob = xbufs[s & 1];
    if (s == 0)
      gemm_k<F_ASHARED | F_OUTHL, 3><<<768, 512, 0, stream>>>(HHL, A8,
          Wq_s, Wk_s, Wv_s, WLO, nullptr, nullptr, nullptr, nullptr, nullptr,
          bn_gamma, bn_beta, bn_mean, bn_var, nullptr, G, A24);
    else
      gemm_k<F_OUTHL, 3><<<768, 512, 0, stream>>>(inb, A24,
          Wq_s, Wk_s, Wv_s, WLO, nullptr, nullptr, nullptr, nullptr, nullptr,
          bn_gamma, bn_beta, bn_mean, bn_var, nullptr, G, A24);
    const float* bq = bq_mp + i * 256;
    const float* bk = bk_mp + i * 256;
    const float* bv = bv_mp + i * 256;
    if (s == 5)
      agg_k<F_BIAS | F_SILU | F_MASKPOST><<<12288, 256, 0, stream>>>(
          G, A24, ob, A24, bq, bk, bv, mask, CNT, IDX);
    else
      agg_k<F_BIAS | F_SILU><<<12288, 256, 0, stream>>>(
          G, A24, ob, A24, bq, bk, bv, mask, CNT, IDX);
  }
  // finals (hi/lo): q = XB+0, k = XB+8*MSZ, v = XB+16*MSZ (lo at +A24)

  // --- attention projections ---
  gemm_k<F_OUTHL, 1><<<256, 512, 0, stream>>>(XB, A24,
      WSZ + (size_t)12 * 65536, nullptr, nullptr, WLO,
      nullptr, nullptr, nullptr, nullptr, nullptr,
      bn_gamma, bn_beta, bn_mean, bn_var, nullptr, PQHL, A8);
  gemm_k<F_SILU | F_MASKPRE | F_TPLANES, 1><<<256, 512, 0, stream>>>(XB + 8 * MSZ, A24,
      WSZ + (size_t)10 * 65536, nullptr, nullptr, WLO,
      nullptr, nullptr, nullptr, mask, nullptr,
      bn_gamma, bn_beta, bn_mean, bn_var, nullptr, PKT, 0);
  gemm_k<F_MASKPOST | F_TPLANES, 1><<<256, 512, 0, stream>>>(XB + 16 * MSZ, A24,
      WSZ + (size_t)11 * 65536, nullptr, nullptr, WLO,
      nullptr, nullptr, nullptr, mask, nullptr,
      bn_gamma, bn_beta, bn_mean, bn_var, nullptr, PVT, 0);

  // --- kv = pk^T pv ---
  kv_k<<<dim3(2, 2, 64), 256, 0, stream>>>(PKT, PVT, KVP);
  kv_conv_k<<<256, 256, 0, stream>>>(KVP, KVS);

  // --- attn = pq @ kv -> hi/lo ---
  gemm_k<F_BPERMAT | F_OUTHL, 1><<<256, 512, 0, stream>>>(PQHL, A8,
      KVS, nullptr, nullptr, KLO,
      nullptr, nullptr, nullptr, nullptr, nullptr,
      bn_gamma, bn_beta, bn_mean, bn_var, nullptr, ATT, A8);

  // --- y = BN(attn @ Wo + x) -> hi/lo ---
  gemm_k<F_ADDX | F_BN | F_OUTHL, 1><<<256, 512, 0, stream>>>(ATT, A8,
      WSZ + (size_t)13 * 65536, nullptr, nullptr, WLO,
      nullptr, nullptr, nullptr, nullptr, x,
      bn_gamma, bn_beta, bn_mean, bn_var, nullptr, YHL, A8);

  // --- tmp = x @ W_res + b_res (fp32) ---
  gemm_k<F_BIAS, 1><<<256, 512, 0, stream>>>(XHL, A8,
      WSZ + (size_t)15 * 65536, nullptr, nullptr, WLO,
      b_res, nullptr, nullptr, nullptr, nullptr,
      bn_gamma, bn_beta, bn_mean, bn_var, nullptr, TMP, 0);

  // --- out = (silu(y @ W_proj + b_proj) + tmp) * mask -> fp32 d_out ---
  gemm_k<F_BIAS | F_SILU | F_ADDT | F_MASKPOST, 1><<<256, 512, 0, stream>>>(YHL, A8,
      WSZ + (size_t)14 * 65536, nullptr, nullptr, WLO,
      b_proj, nullptr, nullptr, mask, nullptr,
      bn_gamma, bn_beta, bn_mean, bn_var, TMP, d_out, 0);

  (void)in_sizes; (void)n_in; (void)out_size; (void)ws_size;
}

// Round 10
// 823.040 us; speedup vs baseline: 1.2539x; 1.2539x over previous
//
#include <hip/hip_runtime.h>
#include <stdint.h>

#define NB 8
#define NN 2048
#define NU 256
#define CAP 64
#define BNEPS 0.001f

typedef __attribute__((ext_vector_type(8))) short short8;
typedef __attribute__((ext_vector_type(4))) float floatx4;
typedef unsigned short u16;
typedef unsigned int u32;

__device__ __forceinline__ float bf2f(u16 u) {
  union { u32 i; float f; } c; c.i = ((u32)u) << 16; return c.f;
}
__device__ __forceinline__ u16 f2bf(float f) {
  union { float f; u32 i; } c; c.f = f;
  return (u16)((c.i + 0x7fffu + ((c.i >> 16) & 1u)) >> 16);
}
// bf16 hi/lo split: a = bf2f(h) + bf2f(l) + O(2^-18 |a|)
__device__ __forceinline__ void splitbf(float a, u16& h, u16& l) {
  h = f2bf(a);
  l = f2bf(a - bf2f(h));
}

enum : unsigned {
  F_BIAS = 2u, F_SILU = 4u, F_MASKPRE = 8u, F_MASKPOST = 16u,
  F_ADDX = 32u, F_BN = 64u, F_ADDT = 128u, F_BPERMAT = 512u,
  F_TPLANES = 1024u, F_OUTHL = 2048u
};

#define TP_MAT 524288   // per-batch transposed plane: 256 cols x 2048 rows (u16)
#define TP_LO  4194304  // transposed lo plane offset (u16 elems)
#define MSZ ((size_t)NN * NU)

// ---------------------------------------------------------------------------
// Neighbor-list build: one block per (b, m) row of adj; values are exactly 0/1.
// ---------------------------------------------------------------------------
__global__ __launch_bounds__(256) void build_nbr_k(
    const float* __restrict__ adj, int* __restrict__ cnt, int* __restrict__ idx)
{
  int row = blockIdx.x;  // b*NN + m
  const float* base = adj + (size_t)row * NN;
  __shared__ int c;
  if (threadIdx.x == 0) c = 0;
  __syncthreads();
#pragma unroll
  for (int j = 0; j < 8; j++) {
    int n = j * 256 + threadIdx.x;  // coalesced
    if (base[n] != 0.f) {
      int p = atomicAdd(&c, 1);
      if (p < CAP) idx[(size_t)row * CAP + p] = n;
    }
  }
  __syncthreads();
  if (threadIdx.x == 0) cnt[row] = (c < CAP ? c : CAP);
}

// ---------------------------------------------------------------------------
// Weight conversion: f32 [K=256][N=256] -> TWO bf16 swizzled-B^T planes
// dst[kb][n][slot][j] = part(W[kb*32 + qv*8 + j][n]), qv = (slot - (n>>1)) & 3
// ---------------------------------------------------------------------------
struct WPtrs { const float* p[16]; };

__global__ __launch_bounds__(256) void conv_w_k(WPtrs wp, u16* __restrict__ dst)
{
  int gid = blockIdx.x * 256 + threadIdx.x;  // 16 mats * 8192 chunks
  int mat = gid >> 13;
  int rem = gid & 8191;
  int kb = rem >> 10;
  int n = (rem >> 2) & 255;
  int slot = rem & 3;
  int qv = (slot - (n >> 1)) & 3;
  int k0 = kb * 32 + qv * 8;
  const float* W = wp.p[mat];
  u32 oh[4], ol[4];
#pragma unroll
  for (int t2 = 0; t2 < 4; t2++) {
    float f0 = W[(size_t)(k0 + 2 * t2) * 256 + n];
    float f1 = W[(size_t)(k0 + 2 * t2 + 1) * 256 + n];
    u16 h0, l0, h1, l1;
    splitbf(f0, h0, l0);
    splitbf(f1, h1, l1);
    oh[t2] = (u32)h0 | ((u32)h1 << 16);
    ol[t2] = (u32)l0 | ((u32)l1 << 16);
  }
  uint4 qh; qh.x = oh[0]; qh.y = oh[1]; qh.z = oh[2]; qh.w = oh[3];
  uint4 ql; ql.x = ol[0]; ql.y = ol[1]; ql.z = ol[2]; ql.w = ol[3];
  *(uint4*)(dst + (size_t)gid * 8) = qh;
  *(uint4*)(dst + 1048576 + (size_t)gid * 8) = ql;  // lo plane at +16*65536
}

// Convert fp32 x (8 mats) -> row-major hi/lo bf16 planes (lo at +oLo elems).
__global__ __launch_bounds__(256) void conv_x_k(
    const float* __restrict__ x, u16* __restrict__ dst, size_t oLo)
{
  size_t i = ((size_t)blockIdx.x * 256 + threadIdx.x) * 4;
  float4 v = *(const float4*)(x + i);
  u16 h0, l0, h1, l1, h2, l2, h3, l3;
  splitbf(v.x, h0, l0); splitbf(v.y, h1, l1);
  splitbf(v.z, h2, l2); splitbf(v.w, h3, l3);
  uint2 H; H.x = (u32)h0 | ((u32)h1 << 16); H.y = (u32)h2 | ((u32)h3 << 16);
  uint2 L; L.x = (u32)l0 | ((u32)l1 << 16); L.y = (u32)l2 | ((u32)l3 << 16);
  *(uint2*)(dst + i) = H;
  *(uint2*)(dst + oLo + i) = L;
}

// ---------------------------------------------------------------------------
// Per-chain epilogue (compile-time flags). Wave layout: 64 rows x 32 cols
// (mt=4 row tiles, nt=2 col tiles), wave w owns cols [w*32, w*32+32).
// ---------------------------------------------------------------------------
template <unsigned F>
__device__ __forceinline__ void gemm_epi(
    floatx4 (&acc)[4][2], int b, int bm, int w, int m16, int q,
    const float* __restrict__ bias, const float* __restrict__ mask,
    const float* __restrict__ xf32,
    const float* __restrict__ gma, const float* __restrict__ bta,
    const float* __restrict__ bmu, const float* __restrict__ bvr,
    const float* __restrict__ addt, void* __restrict__ outp, size_t oLo)
{
#pragma unroll
  for (int mt = 0; mt < 4; mt++) {
    if (F & F_TPLANES) {
      u16* oh = (u16*)outp + (size_t)b * TP_MAT;
      u16* ol = oh + TP_LO;
      int gr0 = bm + mt * 16 + q * 4;
#pragma unroll
      for (int nt = 0; nt < 2; nt++) {
        int col = w * 32 + nt * 16 + m16;
        u16 hh[4], ll[4];
#pragma unroll
        for (int r = 0; r < 4; r++) {
          float t2 = acc[mt][nt][r];
          float mv = mask[b * NN + gr0 + r];
          if (F & F_MASKPRE) t2 *= mv;
          if (F & F_SILU) t2 = t2 / (1.f + __expf(-t2));
          if (F & F_MASKPOST) t2 *= mv;
          splitbf(t2, hh[r], ll[r]);
        }
        uint2 H2, L2v;
        H2.x = (u32)hh[0] | ((u32)hh[1] << 16);
        H2.y = (u32)hh[2] | ((u32)hh[3] << 16);
        L2v.x = (u32)ll[0] | ((u32)ll[1] << 16);
        L2v.y = (u32)ll[2] | ((u32)ll[3] << 16);
        *(uint2*)(oh + (size_t)col * 2048 + gr0) = H2;
        *(uint2*)(ol + (size_t)col * 2048 + gr0) = L2v;
      }
    } else {
#pragma unroll
      for (int r = 0; r < 4; r++) {
        int gr = bm + mt * 16 + q * 4 + r;
        float mval = 1.f;
        if (F & (F_MASKPRE | F_MASKPOST)) mval = mask[b * NN + gr];
#pragma unroll
        for (int nt = 0; nt < 2; nt++) {
          int col = w * 32 + nt * 16 + m16;
          float t2 = acc[mt][nt][r];
          if (F & F_BIAS) t2 += bias[col];
          if (F & F_MASKPRE) t2 *= mval;
          if (F & F_SILU) t2 = t2 / (1.f + __expf(-t2));
          if (F & F_ADDX) t2 += xf32[((size_t)b * NN + gr) * NU + col];
          if (F & F_BN) t2 = gma[col] * (t2 - bmu[col]) * rsqrtf(bvr[col] + BNEPS) + bta[col];
          if (F & F_ADDT) t2 += addt[((size_t)b * NN + gr) * NU + col];
          if (F & F_MASKPOST) t2 *= mval;
          size_t o = ((size_t)b * NN + gr) * NU + col;
          if (F & F_OUTHL) {
            u16 h0, l0;
            splitbf(t2, h0, l0);
            ((u16*)outp)[o] = h0;
            ((u16*)outp)[o + oLo] = l0;
          } else {
            ((float*)outp)[o] = t2;
          }
        }
      }
    }
  }
}

// ---------------------------------------------------------------------------
// Dense GEMM, fp32-emulated via bf16 hi/lo 3-term MFMA. Up to 3 fused chains
// with per-chain A/W/bias/out/epilogue-flags (chain is block-uniform).
// Tile 64 rows x 256 cols, 512 thr = 8 waves, each 64x32 (B unique per wave).
// A: pre-split hi/lo planes, pure-copy staged to LDS (67.6 KB -> 2 blocks/CU).
// B: per-lane fragments straight from swizzled global planes (L2-hot).
// Grid 1-D 256*NG, xcd = id&7.
// ---------------------------------------------------------------------------
template <int NG, unsigned F0, unsigned F1, unsigned F2>
__global__ __launch_bounds__(512, 4) void gemm_k(
    const u16* __restrict__ A0, const u16* __restrict__ A1, const u16* __restrict__ A2,
    size_t aLo,
    const u16* __restrict__ W0, const u16* __restrict__ W1, const u16* __restrict__ W2,
    size_t wLo,
    const float* __restrict__ b0, const float* __restrict__ b1, const float* __restrict__ b2,
    const float* __restrict__ mask,
    const float* __restrict__ xf32,
    const float* __restrict__ gma, const float* __restrict__ bta,
    const float* __restrict__ bmu, const float* __restrict__ bvr,
    const float* __restrict__ addt,
    void* __restrict__ o0, void* __restrict__ o1, void* __restrict__ o2,
    size_t oLo)
{
  const int tid = threadIdx.x;
  const int id = blockIdx.x;
  const int xcd = id & 7;
  const int t = id >> 3;
  const int chain = (NG == 1) ? 0 : (t % NG);
  const int xt = (NG == 1) ? t : (t / NG);
  const int b = xcd;
  const int bm = xt * 64;

  __shared__ alignas(16) u16 Ah[64 * 264];  // 33792 B
  __shared__ alignas(16) u16 Al[64 * 264];  // 33792 B -> 67584 B total

  const u16* Abase = (chain == 0) ? A0 : (chain == 1 ? A1 : A2);
  const u16* Wsel = (chain == 0) ? W0 : (chain == 1 ? W1 : W2);
  if (F0 & F_BPERMAT) Wsel = W0 + (size_t)b * 65536;  // NG==1 only
  const u16* Whi = Wsel;
  const u16* Wlo = Whi + wLo;
  const u16* Ahp = Abase + (size_t)b * MSZ;
  const u16* Alp = Ahp + aLo;

  // ---- stage A tile (64 x 256) hi/lo: pure copies ----
#pragma unroll
  for (int s = tid; s < 1024; s += 512) {
    int r = s >> 4;
    int c = (s & 15) << 4;
    size_t ao = (size_t)(bm + r) * 256 + c;
    *(uint4*)&Ah[r * 264 + c] = *(const uint4*)(Ahp + ao);
    *(uint4*)&Ah[r * 264 + c + 8] = *(const uint4*)(Ahp + ao + 8);
    *(uint4*)&Al[r * 264 + c] = *(const uint4*)(Alp + ao);
    *(uint4*)&Al[r * 264 + c + 8] = *(const uint4*)(Alp + ao + 8);
  }
  __syncthreads();

  const int lane = tid & 63;
  const int w = tid >> 6;      // 8 waves, each owns 32 cols
  const int m16 = lane & 15;
  const int q = lane >> 4;

  floatx4 acc[4][2];
#pragma unroll
  for (int i = 0; i < 4; i++)
#pragma unroll
    for (int j = 0; j < 2; j++) acc[i][j] = (floatx4){0.f, 0.f, 0.f, 0.f};

#pragma unroll
  for (int kk = 0; kk < 8; kk++) {
    short8 bh[2], bl2[2];
#pragma unroll
    for (int nt = 0; nt < 2; nt++) {
      int n = w * 32 + nt * 16 + m16;
      size_t off = (size_t)kk * 8192 + (size_t)n * 32 + (size_t)(((q + (n >> 1)) & 3) * 8);
      bh[nt] = *(const short8*)(Whi + off);
      bl2[nt] = *(const short8*)(Wlo + off);
    }
#pragma unroll
    for (int mt = 0; mt < 4; mt++) {
      int row = mt * 16 + m16;
      short8 ah = *(const short8*)&Ah[row * 264 + kk * 32 + q * 8];
      short8 al2 = *(const short8*)&Al[row * 264 + kk * 32 + q * 8];
#pragma unroll
      for (int nt = 0; nt < 2; nt++) {
        acc[mt][nt] = __builtin_amdgcn_mfma_f32_16x16x32_bf16(ah, bh[nt], acc[mt][nt], 0, 0, 0);
        acc[mt][nt] = __builtin_amdgcn_mfma_f32_16x16x32_bf16(al2, bh[nt], acc[mt][nt], 0, 0, 0);
        acc[mt][nt] = __builtin_amdgcn_mfma_f32_16x16x32_bf16(ah, bl2[nt], acc[mt][nt], 0, 0, 0);
      }
    }
  }

  if (NG == 1 || chain == 0)
    gemm_epi<F0>(acc, b, bm, w, m16, q, b0, mask, xf32, gma, bta, bmu, bvr, addt, o0, oLo);
  else if (chain == 1)
    gemm_epi<F1>(acc, b, bm, w, m16, q, b1, mask, xf32, gma, bta, bmu, bvr, addt, o1, oLo);
  else
    gemm_epi<F2>(acc, b, bm, w, m16, q, b2, mask, xf32, gma, bta, bmu, bvr, addt, o2, oLo);
}

// ---------------------------------------------------------------------------
// Fused 3-chain gather: x'[c][m] = epi( sum_{n in nbr(m)} g[c][n] + bias[c] ).
// g fp32 (2 MB per (chain,b) mat -> L2-resident), out hi/lo bf16 planes.
// One wave per row. Grid 12288, chain-major (c = id>>12).
// ---------------------------------------------------------------------------
template <unsigned F>
__global__ __launch_bounds__(256, 8) void agg_k(
    const float* __restrict__ g, u16* __restrict__ xo, size_t oLo,
    const float* __restrict__ bq, const float* __restrict__ bk, const float* __restrict__ bv,
    const float* __restrict__ mask,
    const int* __restrict__ ncnt, const int* __restrict__ nidx)
{
  int id = blockIdx.x;
  int c3 = id >> 12;       // chain 0..2
  int sub = id & 4095;
  int b = sub & 7;
  int rg = sub >> 3;
  int tid = threadIdx.x;
  int w = tid >> 6;
  int l = tid & 63;
  int row = rg * 4 + w;
  int rowid = b * NN + row;
  const float* __restrict__ gm = g + ((size_t)c3 * 8 + b) * MSZ;
  const float* bias = (c3 == 0) ? bq : (c3 == 1 ? bk : bv);
  int cnt = ncnt[rowid];
  const int* __restrict__ ip = nidx + (size_t)rowid * CAP;
  int c = l * 4;
  float4 a; a.x = a.y = a.z = a.w = 0.f;
  int e = 0;
  for (; e + 4 <= cnt; e += 4) {
    int4 i4 = *(const int4*)(ip + e);
    float4 v0 = *(const float4*)(gm + ((size_t)i4.x << 8) + c);
    float4 v1 = *(const float4*)(gm + ((size_t)i4.y << 8) + c);
    float4 v2 = *(const float4*)(gm + ((size_t)i4.z << 8) + c);
    float4 v3 = *(const float4*)(gm + ((size_t)i4.w << 8) + c);
    a.x += v0.x + v1.x + v2.x + v3.x;
    a.y += v0.y + v1.y + v2.y + v3.y;
    a.z += v0.z + v1.z + v2.z + v3.z;
    a.w += v0.w + v1.w + v2.w + v3.w;
  }
  for (; e < cnt; e++) {
    float4 v = *(const float4*)(gm + ((size_t)ip[e] << 8) + c);
    a.x += v.x; a.y += v.y; a.z += v.z; a.w += v.w;
  }
  float4 bb = *(const float4*)(bias + c);
  float o[4] = {a.x + bb.x, a.y + bb.y, a.z + bb.z, a.w + bb.w};
  float mv = (F & F_MASKPOST) ? mask[rowid] : 1.f;
  u16 hh[4], ll[4];
#pragma unroll
  for (int j = 0; j < 4; j++) {
    float t = o[j];
    if (F & F_SILU) t = t / (1.f + __expf(-t));
    if (F & F_MASKPOST) t *= mv;
    splitbf(t, hh[j], ll[j]);
  }
  uint2 H; H.x = (u32)hh[0] | ((u32)hh[1] << 16); H.y = (u32)hh[2] | ((u32)hh[3] << 16);
  uint2 L; L.x = (u32)ll[0] | ((u32)ll[1] << 16); L.y = (u32)ll[2] | ((u32)ll[3] << 16);
  size_t o0 = ((size_t)c3 * 8 + b) * MSZ + ((size_t)row << 8) + c;
  *(uint2*)(xo + o0) = H;
  *(uint2*)(xo + oLo + o0) = L;
}

// ---------------------------------------------------------------------------
// kv[d][e] = sum_n pk[n][d] * pv[n][e], from transposed bf16 hi/lo planes.
// LDS-free, 3-term. Split-K=8: part[z = p*8+b][d][e], grid (2,2,64).
// ---------------------------------------------------------------------------
__global__ __launch_bounds__(256, 2) void kv_k(
    const u16* __restrict__ pkT, const u16* __restrict__ pvT, float* __restrict__ part)
{
  int et = blockIdx.x * 128;
  int dt = blockIdx.y * 128;
  int z = blockIdx.z;
  int b = z & 7;
  int p = z >> 3;
  int tid = threadIdx.x;
  int lane = tid & 63, w = tid >> 6;
  int m16 = lane & 15, q = lane >> 4;

  const u16* pkh = pkT + (size_t)b * TP_MAT;
  const u16* pkl = pkh + TP_LO;
  const u16* pvh = pvT + (size_t)b * TP_MAT;
  const u16* pvl = pvh + TP_LO;

  int d_base = dt + (w >> 1) * 64 + m16;
  int e_base = et + (w & 1) * 64 + m16;

  floatx4 acc[4][4];
#pragma unroll
  for (int i = 0; i < 4; i++)
#pragma unroll
    for (int j = 0; j < 4; j++) acc[i][j] = (floatx4){0.f, 0.f, 0.f, 0.f};

#pragma unroll
  for (int kt = 0; kt < 8; kt++) {
    int kc = p * 256 + kt * 32 + q * 8;
    short8 ah[4], al[4], bh[4], bl[4];
#pragma unroll
    for (int mt = 0; mt < 4; mt++) {
      size_t o = (size_t)(d_base + mt * 16) * 2048 + kc;
      ah[mt] = *(const short8*)(pkh + o);
      al[mt] = *(const short8*)(pkl + o);
    }
#pragma unroll
    for (int nt = 0; nt < 4; nt++) {
      size_t o = (size_t)(e_base + nt * 16) * 2048 + kc;
      bh[nt] = *(const short8*)(pvh + o);
      bl[nt] = *(const short8*)(pvl + o);
    }
#pragma unroll
    for (int mt = 0; mt < 4; mt++)
#pragma unroll
      for (int nt = 0; nt < 4; nt++) {
        acc[mt][nt] = __builtin_amdgcn_mfma_f32_16x16x32_bf16(ah[mt], bh[nt], acc[mt][nt], 0, 0, 0);
        acc[mt][nt] = __builtin_amdgcn_mfma_f32_16x16x32_bf16(al[mt], bh[nt], acc[mt][nt], 0, 0, 0);
        acc[mt][nt] = __builtin_amdgcn_mfma_f32_16x16x32_bf16(ah[mt], bl[nt], acc[mt][nt], 0, 0, 0);
      }
  }

#pragma unroll
  for (int mt = 0; mt < 4; mt++)
#pragma unroll
    for (int r = 0; r < 4; r++) {
      int d = dt + (w >> 1) * 64 + mt * 16 + q * 4 + r;
#pragma unroll
      for (int nt = 0; nt < 4; nt++) {
        int e = et + (w & 1) * 64 + nt * 16 + m16;
        part[(size_t)z * 65536 + (size_t)d * 256 + e] = acc[mt][nt][r];
      }
    }
}

// Reduce split-K partials (8 p-planes) and emit kv bf16 hi/lo swizzled planes.
__global__ __launch_bounds__(256) void kv_conv_k(const float* __restrict__ part, u16* __restrict__ dst)
{
  int gid = blockIdx.x * 256 + threadIdx.x;  // 8 * 8192 = 65536
  int b = gid >> 13;
  int rem = gid & 8191;
  int kb = rem >> 10;
  int e = (rem >> 2) & 255;
  int slot = rem & 3;
  int qv = (slot - (e >> 1)) & 3;
  int d0 = kb * 32 + qv * 8;
  const float* src = part + (size_t)b * 65536 + (size_t)d0 * 256 + e;
  u32 oh[4], ol[4];
#pragma unroll
  for (int t2 = 0; t2 < 4; t2++) {
    float s0 = 0.f, s1 = 0.f;
#pragma unroll
    for (int pp = 0; pp < 8; pp++) {
      const float* sp = src + (size_t)pp * 524288 + t2 * 512;
      s0 += sp[0];
      s1 += sp[256];
    }
    u16 h0, l0, h1, l1;
    splitbf(s0, h0, l0);
    splitbf(s1, h1, l1);
    oh[t2] = (u32)h0 | ((u32)h1 << 16);
    ol[t2] = (u32)l0 | ((u32)l1 << 16);
  }
  uint4 qh; qh.x = oh[0]; qh.y = oh[1]; qh.z = oh[2]; qh.w = oh[3];
  uint4 ql; ql.x = ol[0]; ql.y = ol[1]; ql.z = ol[2]; ql.w = ol[3];
  *(uint4*)(dst + (size_t)gid * 8) = qh;
  *(uint4*)(dst + 524288 + (size_t)gid * 8) = ql;  // lo plane at +8*65536
}

// ---------------------------------------------------------------------------
extern "C" void kernel_launch(void* const* d_in, const int* in_sizes, int n_in,
                              void* d_out, int out_size, void* d_ws, size_t ws_size,
                              hipStream_t stream)
{
  const float* x = (const float*)d_in[0];
  const float* adj = (const float*)d_in[1];
  const float* mask = (const float*)d_in[2];
  const float* W_lin = (const float*)d_in[3];
  const float* b_lin = (const float*)d_in[4];
  const float* Wq_mp = (const float*)d_in[5];
  const float* bq_mp = (const float*)d_in[6];
  const float* Wk_mp = (const float*)d_in[7];
  const float* bk_mp = (const float*)d_in[8];
  const float* Wv_mp = (const float*)d_in[9];
  const float* bv_mp = (const float*)d_in[10];
  const float* Wk_att = (const float*)d_in[11];
  const float* Wv_att = (const float*)d_in[12];
  const float* Wq_att = (const float*)d_in[13];
  const float* Wo_att = (const float*)d_in[14];
  const float* bn_gamma = (const float*)d_in[15];
  const float* bn_beta = (const float*)d_in[16];
  const float* bn_mean = (const float*)d_in[17];
  const float* bn_var = (const float*)d_in[18];
  const float* W_proj = (const float*)d_in[19];
  const float* b_proj = (const float*)d_in[20];
  const float* W_res = (const float*)d_in[21];
  const float* b_res = (const float*)d_in[22];

  char* ws = (char*)d_ws;
  int* CNT    = (int*)(ws + 0);                 // 64 KB
  int* IDX    = (int*)(ws + (1ull << 20));      // 4 MB
  u16* WSZ    = (u16*)(ws + (5ull << 20));      // 4 MB (bf16 hi 2MB + lo 2MB)
  u16* KVS    = (u16*)(ws + (9ull << 20));      // 2 MB
  float* KVP  = (float*)(ws + (11ull << 20));   // 16 MB
  u16* XHL    = (u16*)(ws + (27ull << 20));     // 16 MB (8 hi + 8 lo)
  u16* HHL    = (u16*)(ws + (43ull << 20));     // 16 MB (8 hi + 8 lo)
  float* G    = (float*)(ws + (59ull << 20));   // 48 MB fp32 (24 mats)
  u16* XA     = (u16*)(ws + (107ull << 20));    // 48 MB (24 hi + 24 lo)
  u16* XB     = (u16*)(ws + (155ull << 20));    // 48 MB -> total 203 MB

  const size_t WLO = 1048576;   // weight lo-plane offset (u16 elems)
  const size_t KLO = 524288;    // kv lo-plane offset
  const size_t A8  = 8 * MSZ;   // lo offset for 8-mat hi/lo buffers
  const size_t A24 = 24 * MSZ;  // lo offset for 24-mat hi/lo buffers

  u16* PQHL = HHL;                         // h dead after s0 GEMM
  u16* PKT = (u16*)G;                      // G dead after s5 agg
  u16* PVT = (u16*)((char*)G + (16ull << 20));
  u16* ATT = (u16*)((char*)G + (32ull << 20));
  u16* YHL = XA;                           // XA dead after s5 GEMM
  float* TMP = (float*)((char*)XA + (16ull << 20));

  // --- conversions + neighbor lists ---
  WPtrs wp;
  wp.p[0] = W_lin;
  wp.p[1] = Wq_mp; wp.p[2] = Wq_mp + 65536; wp.p[3] = Wq_mp + 131072;
  wp.p[4] = Wk_mp; wp.p[5] = Wk_mp + 65536; wp.p[6] = Wk_mp + 131072;
  wp.p[7] = Wv_mp; wp.p[8] = Wv_mp + 65536; wp.p[9] = Wv_mp + 131072;
  wp.p[10] = Wk_att; wp.p[11] = Wv_att; wp.p[12] = Wq_att; wp.p[13] = Wo_att;
  wp.p[14] = W_proj; wp.p[15] = W_res;
  conv_w_k<<<512, 256, 0, stream>>>(wp, WSZ);
  conv_x_k<<<4096, 256, 0, stream>>>(x, XHL, A8);
  build_nbr_k<<<NB * NN, 256, 0, stream>>>(adj, CNT, IDX);

  // --- h = x @ W_lin + b_lin -> hi/lo planes ---
  gemm_k<1, F_BIAS | F_OUTHL, 0u, 0u><<<256, 512, 0, stream>>>(
      XHL, XHL, XHL, A8, WSZ, WSZ, WSZ, WLO,
      b_lin, nullptr, nullptr, mask, nullptr,
      bn_gamma, bn_beta, bn_mean, bn_var, nullptr,
      HHL, nullptr, nullptr, A8);

  // --- 6 mp steps: g = x@W (dense fp32 out), x' = silu(adj@g + b) (gather) ---
  u16* xbufs[2] = {XA, XB};
  for (int s = 0; s < 6; s++) {
    int i = s >> 1;
    const u16* Wq_s = WSZ + (size_t)(1 + i) * 65536;
    const u16* Wk_s = WSZ + (size_t)(4 + i) * 65536;
    const u16* Wv_s = WSZ + (size_t)(7 + i) * 65536;
    u16* inb = (s == 0) ? HHL : xbufs[(s + 1) & 1];
    size_t aLo = (s == 0) ? A8 : A24;
    const u16* Aq = inb;
    const u16* Ak = (s == 0) ? inb : inb + 8 * MSZ;
    const u16* Av = (s == 0) ? inb : inb + 16 * MSZ;
    u16* ob = xbufs[s & 1];
    gemm_k<3, 0u, 0u, 0u><<<768, 512, 0, stream>>>(
        Aq, Ak, Av, aLo, Wq_s, Wk_s, Wv_s, WLO,
        nullptr, nullptr, nullptr, mask, nullptr,
        bn_gamma, bn_beta, bn_mean, bn_var, nullptr,
        G, G + 8 * MSZ, G + 16 * MSZ, 0);
    const float* bq = bq_mp + i * 256;
    const float* bk = bk_mp + i * 256;
    const float* bv = bv_mp + i * 256;
    if (s == 5)
      agg_k<F_BIAS | F_SILU | F_MASKPOST><<<12288, 256, 0, stream>>>(
          G, ob, A24, bq, bk, bv, mask, CNT, IDX);
    else
      agg_k<F_BIAS | F_SILU><<<12288, 256, 0, stream>>>(
          G, ob, A24, bq, bk, bv, mask, CNT, IDX);
  }
  // finals (hi/lo): q = XB+0, k = XB+8*MSZ, v = XB+16*MSZ (lo at +A24)

  // --- attention projections, fused (pq | pk | pv) ---
  gemm_k<3, F_OUTHL, F_SILU | F_MASKPRE | F_TPLANES, F_MASKPOST | F_TPLANES>
      <<<768, 512, 0, stream>>>(
      XB, XB + 8 * MSZ, XB + 16 * MSZ, A24,
      WSZ + (size_t)12 * 65536, WSZ + (size_t)10 * 65536, WSZ + (size_t)11 * 65536, WLO,
      nullptr, nullptr, nullptr, mask, nullptr,
      bn_gamma, bn_beta, bn_mean, bn_var, nullptr,
      PQHL, PKT, PVT, A8);

  // --- kv = pk^T pv ---
  kv_k<<<dim3(2, 2, 64), 256, 0, stream>>>(PKT, PVT, KVP);
  kv_conv_k<<<256, 256, 0, stream>>>(KVP, KVS);

  // --- attn = pq @ kv -> hi/lo ---
  gemm_k<1, F_BPERMAT | F_OUTHL, 0u, 0u><<<256, 512, 0, stream>>>(
      PQHL, PQHL, PQHL, A8, KVS, KVS, KVS, KLO,
      nullptr, nullptr, nullptr, mask, nullptr,
      bn_gamma, bn_beta, bn_mean, bn_var, nullptr,
      ATT, nullptr, nullptr, A8);

  // --- y = BN(attn @ Wo + x) -> hi/lo ---
  gemm_k<1, F_ADDX | F_BN | F_OUTHL, 0u, 0u><<<256, 512, 0, stream>>>(
      ATT, ATT, ATT, A8,
      WSZ + (size_t)13 * 65536, nullptr, nullptr, WLO,
      nullptr, nullptr, nullptr, mask, x,
      bn_gamma, bn_beta, bn_mean, bn_var, nullptr,
      YHL, nullptr, nullptr, A8);

  // --- tmp = x @ W_res + b_res (fp32) ---
  gemm_k<1, F_BIAS, 0u, 0u><<<256, 512, 0, stream>>>(
      XHL, XHL, XHL, A8,
      WSZ + (size_t)15 * 65536, nullptr, nullptr, WLO,
      b_res, nullptr, nullptr, mask, nullptr,
      bn_gamma, bn_beta, bn_mean, bn_var, nullptr,
      TMP, nullptr, nullptr, 0);

  // --- out = (silu(y @ W_proj + b_proj) + tmp) * mask -> fp32 d_out ---
  gemm_k<1, F_BIAS | F_SILU | F_ADDT | F_MASKPOST, 0u, 0u><<<256, 512, 0, stream>>>(
      YHL, YHL, YHL, A8,
      WSZ + (size_t)14 * 65536, nullptr, nullptr, WLO,
      b_proj, nullptr, nullptr, mask, nullptr,
      bn_gamma, bn_beta, bn_mean, bn_var, TMP,
      d_out, nullptr, nullptr, 0);

  (void)in_sizes; (void)n_in; (void)out_size; (void)ws_size;
}